// Round 7
// baseline (646.504 us; speedup 1.0000x reference)
//
#include <hip/hip_runtime.h>
#include <hip/hip_fp16.h>
#include <math.h>
#include <type_traits>

static constexpr int THREADS = 256;
static constexpr int CAP    = 80;      // bucket capacity; in-deg ~Poisson(32), P(any >= 80) ~ 5e-8
static constexpr int BSH    = 12;      // dst-bucket shift: 4096 nodes/bucket
static constexpr int CAPB   = 137216;  // per-bucket pair capacity (mean 131072 + >10 sigma)
static constexpr int MAXB   = 64;      // max buckets supported

// ---------------- CSR build phase 0: zero cnt (n) + bcnt (MAXB, adjacent) ----------------

__global__ void k_zero_i(int* __restrict__ p, int n) {
    int i = blockIdx.x * blockDim.x + threadIdx.x;
    if (i < n) p[i] = 0;
}

// ---------------- phase 1: partition edges into dst-range bucket streams ----------------
// Read edges ONCE; LDS histogram -> one global atomicAdd per (bucket, block);
// pairs packed as ((d & 4095) << 17) | s   (requires n <= 131072).

__global__ __launch_bounds__(THREADS)
void k_part(const int* __restrict__ src, const int* __restrict__ dst,
            int* __restrict__ bcnt, int* __restrict__ pairs, int e, int nbuck) {
    __shared__ int hist[MAXB];
    __shared__ int base_s[MAXB];
    for (int i = threadIdx.x; i < nbuck; i += THREADS) hist[i] = 0;
    __syncthreads();

    int i0 = (blockIdx.x * THREADS + (int)threadIdx.x) * 8;
    int ss[8], dd[8], bb[8], rk[8];
    int c8 = 0;
    if (i0 < e) {
        c8 = min(8, e - i0);
        if (c8 == 8) {
            int4 d0 = ((const int4*)(dst + i0))[0];
            int4 d1 = ((const int4*)(dst + i0))[1];
            int4 s0 = ((const int4*)(src + i0))[0];
            int4 s1 = ((const int4*)(src + i0))[1];
            dd[0]=d0.x; dd[1]=d0.y; dd[2]=d0.z; dd[3]=d0.w;
            dd[4]=d1.x; dd[5]=d1.y; dd[6]=d1.z; dd[7]=d1.w;
            ss[0]=s0.x; ss[1]=s0.y; ss[2]=s0.z; ss[3]=s0.w;
            ss[4]=s1.x; ss[5]=s1.y; ss[6]=s1.z; ss[7]=s1.w;
        } else {
            for (int j = 0; j < c8; ++j) { dd[j] = dst[i0 + j]; ss[j] = src[i0 + j]; }
        }
        for (int j = 0; j < c8; ++j) {
            bb[j] = dd[j] >> BSH;
            rk[j] = atomicAdd(&hist[bb[j]], 1);
        }
    }
    __syncthreads();
    for (int i = threadIdx.x; i < nbuck; i += THREADS)
        base_s[i] = hist[i] ? atomicAdd(&bcnt[i], hist[i]) : 0;
    __syncthreads();
    for (int j = 0; j < c8; ++j) {
        int idx = base_s[bb[j]] + rk[j];
        if (idx < CAPB)
            pairs[(size_t)bb[j] * CAPB + idx] = ((dd[j] & ((1 << BSH) - 1)) << 17) | ss[j];
    }
}

// ---------------- phase 2: scatter bucket streams into csr; one block per bucket ----------------
// 25 blocks over 8 XCDs -> ~3 x 1.3 MB windows per XCD L2: scattered writes combine.

__global__ __launch_bounds__(1024)
void k_scat(const int* __restrict__ pairs, const int* __restrict__ bcnt,
            int* __restrict__ cnt, int* __restrict__ csr) {
    int b = blockIdx.x;
    int m = min(bcnt[b], CAPB);
    const int* pp = pairs + (size_t)b * CAPB;
    int dbase = b << BSH;
    for (int i0 = (int)threadIdx.x * 8; i0 < m; i0 += 1024 * 8) {
        int k = min(8, m - i0);
        int v[8];
        if (k == 8) {
            int4 a = ((const int4*)(pp + i0))[0];
            int4 c = ((const int4*)(pp + i0))[1];
            v[0]=a.x; v[1]=a.y; v[2]=a.z; v[3]=a.w;
            v[4]=c.x; v[5]=c.y; v[6]=c.z; v[7]=c.w;
        } else {
            for (int j = 0; j < k; ++j) v[j] = pp[i0 + j];
        }
#pragma unroll
        for (int j = 0; j < 8; ++j) {
            if (j < k) {
                int d = dbase + (v[j] >> 17);
                int s = v[j] & 0x1FFFF;
                int p = atomicAdd(&cnt[d], 1);
                csr[(size_t)d * CAP + p] = s;
            }
        }
    }
}

// ---------------- dis = rsqrt(deg+1); xs[n][16] = f16(dis*x) (fused) ----------------

__global__ __launch_bounds__(THREADS)
void k_dis_xs(const int* __restrict__ deg, const float* __restrict__ x,
              float* __restrict__ dis, __half2* __restrict__ xs, int n) {
    int i = blockIdx.x * blockDim.x + threadIdx.x;
    if (i >= n) return;
    float dn = rsqrtf((float)(deg[i] + 1));
    dis[i] = dn;
    const float* xr = x + (size_t)i * 14;
    __half2* o = xs + (size_t)i * 8;
#pragma unroll
    for (int fl = 0; fl < 7; ++fl) {
        float2 v;
        v.x = dn * xr[fl * 2];
        v.y = dn * xr[fl * 2 + 1];
        o[fl] = __float22half2_rn(v);
    }
    o[7] = __float22half2_rn(make_float2(0.f, 0.f));
}

// ---------------- CSR gather, packed-f16 accumulate ----------------

template<int SG, int HPL, bool SELF_SCALE, bool EPI_SCALE, bool BIAS, bool RELU>
__global__ __launch_bounds__(THREADS)
void k_gather_pk(const __half2* __restrict__ hw, const int* __restrict__ deg,
                 const int* __restrict__ csr, const float* __restrict__ dis,
                 const float* __restrict__ bias, float* __restrict__ out, int n) {
    constexpr int RS = SG * HPL;   // row stride in half2 units
    int tid = blockIdx.x * THREADS + threadIdx.x;
    int node = tid / SG;
    int fl = tid % SG;
    if (node >= n) return;
    size_t o = (size_t)node * CAP;
    int dg = deg[node];
    float dn = dis[node];

    auto loadrow = [&](int s, __half2* r) {
        const __half2* p = hw + (size_t)s * RS + fl * HPL;
        if constexpr (HPL == 4) {
            union { uint4 u; __half2 h[4]; } t;
            t.u = *(const uint4*)p;
            r[0] = t.h[0]; r[1] = t.h[1]; r[2] = t.h[2]; r[3] = t.h[3];
        } else if constexpr (HPL == 2) {
            union { uint2 u; __half2 h[2]; } t;
            t.u = *(const uint2*)p;
            r[0] = t.h[0]; r[1] = t.h[1];
        } else {
            r[0] = *p;
        }
    };

    // self in f32
    float2 self[HPL];
    {
        __half2 r[HPL];
        loadrow(node, r);
#pragma unroll
        for (int q = 0; q < HPL; ++q) {
            self[q] = __half22float2(r[q]);
            if (SELF_SCALE) { self[q].x *= dn; self[q].y *= dn; }
        }
    }

    __half2 z = __float2half2_rn(0.f);
    __half2 c0[HPL], c1[HPL], c2[HPL], c3[HPL];
#pragma unroll
    for (int q = 0; q < HPL; ++q) { c0[q] = z; c1[q] = z; c2[q] = z; c3[q] = z; }

    int base = 0;
    for (; base + SG <= dg; base += SG) {
        int cs = csr[o + base + fl];
#pragma unroll
        for (int t = 0; t < SG; t += 4) {
            int s0 = __shfl(cs, t, SG),     s1 = __shfl(cs, t + 1, SG);
            int s2 = __shfl(cs, t + 2, SG), s3 = __shfl(cs, t + 3, SG);
            __half2 r0[HPL], r1[HPL], r2[HPL], r3[HPL];
            loadrow(s0, r0); loadrow(s1, r1); loadrow(s2, r2); loadrow(s3, r3);
#pragma unroll
            for (int q = 0; q < HPL; ++q) {
                c0[q] = __hadd2(c0[q], r0[q]);
                c1[q] = __hadd2(c1[q], r1[q]);
                c2[q] = __hadd2(c2[q], r2[q]);
                c3[q] = __hadd2(c3[q], r3[q]);
            }
        }
    }
    int rem = dg - base;
    if (rem > 0) {
        int cs = (fl < rem) ? csr[o + base + fl] : 0;
        int t = 0;
        for (; t + 4 <= rem; t += 4) {
            int s0 = __shfl(cs, t, SG),     s1 = __shfl(cs, t + 1, SG);
            int s2 = __shfl(cs, t + 2, SG), s3 = __shfl(cs, t + 3, SG);
            __half2 r0[HPL], r1[HPL], r2[HPL], r3[HPL];
            loadrow(s0, r0); loadrow(s1, r1); loadrow(s2, r2); loadrow(s3, r3);
#pragma unroll
            for (int q = 0; q < HPL; ++q) {
                c0[q] = __hadd2(c0[q], r0[q]);
                c1[q] = __hadd2(c1[q], r1[q]);
                c2[q] = __hadd2(c2[q], r2[q]);
                c3[q] = __hadd2(c3[q], r3[q]);
            }
        }
        for (; t < rem; ++t) {
            int s = __shfl(cs, t, SG);
            __half2 r[HPL];
            loadrow(s, r);
#pragma unroll
            for (int q = 0; q < HPL; ++q) c0[q] = __hadd2(c0[q], r[q]);
        }
    }

    float* op = out + (size_t)node * 2 * RS + fl * 2 * HPL;
#pragma unroll
    for (int q = 0; q < HPL; ++q) {
        float2 v0 = __half22float2(c0[q]), v1 = __half22float2(c1[q]);
        float2 v2 = __half22float2(c2[q]), v3 = __half22float2(c3[q]);
        float2 v;
        v.x = self[q].x + (v0.x + v1.x) + (v2.x + v3.x);
        v.y = self[q].y + (v0.y + v1.y) + (v2.y + v3.y);
        if (EPI_SCALE) { v.x *= dn; v.y *= dn; }
        if (BIAS) {
            float2 b = ((const float2*)bias)[fl * HPL + q];
            v.x += b.x; v.y += b.y;
        }
        if (RELU) { v.x = fmaxf(v.x, 0.f); v.y = fmaxf(v.y, 0.f); }
        op[q * 2 + 0] = v.x;
        op[q * 2 + 1] = v.y;
    }
}

// F=2 gather: one thread per node, f32 float2 rows (800 KB buffer, L2-resident)
__global__ __launch_bounds__(THREADS)
void k_gather2(const float* __restrict__ hw, const int* __restrict__ deg,
               const int* __restrict__ csr, const float* __restrict__ dis,
               const float* __restrict__ b, float* __restrict__ out, int n) {
    int i = blockIdx.x * blockDim.x + threadIdx.x;
    if (i >= n) return;
    const float2* h2 = (const float2*)hw;
    size_t o = (size_t)i * CAP;
    int dg = deg[i];
    float2 a = h2[i];
    float x0 = a.x, y0 = a.y, x1 = 0.f, y1 = 0.f, x2 = 0.f, y2 = 0.f, x3 = 0.f, y3 = 0.f;
    int j = 0;
    for (; j + 4 <= dg; j += 4) {
        int s0 = csr[o + j], s1 = csr[o + j + 1], s2 = csr[o + j + 2], s3 = csr[o + j + 3];
        float2 v0 = h2[s0], v1 = h2[s1], v2 = h2[s2], v3 = h2[s3];
        x0 += v0.x; y0 += v0.y;
        x1 += v1.x; y1 += v1.y;
        x2 += v2.x; y2 += v2.y;
        x3 += v3.x; y3 += v3.y;
    }
    for (; j < dg; ++j) {
        int s = csr[o + j];
        float2 v = h2[s];
        x0 += v.x; y0 += v.y;
    }
    float dn = dis[i];
    out[(size_t)i * 2 + 0] = ((x0 + x1) + (x2 + x3)) * dn + b[0];
    out[(size_t)i * 2 + 1] = ((y0 + y1) + (y2 + y3)) * dn + b[1];
}

// ---------------- register-blocked GEMM: 2 nodes x 4 cols per thread ----------------

template<int KW, int K, int KSTR, int FOUT, bool EPI_BIAS_RELU, typename OUT_T>
__global__ __launch_bounds__(THREADS)
void k_gemm_rb(const float* __restrict__ in, const float* __restrict__ W,
               const float* __restrict__ dis, const float* __restrict__ bias,
               OUT_T* __restrict__ out, int n) {
    constexpr int CG = FOUT / 4;
    __shared__ float Ws[K * FOUT];
    for (int i = threadIdx.x; i < K * FOUT; i += THREADS) {
        int r = i / FOUT;
        Ws[i] = (r < KW) ? W[i] : 0.0f;
    }
    __syncthreads();
    int gid = blockIdx.x * THREADS + threadIdx.x;
    int pair = gid / CG, cg = gid % CG;
    int node0 = pair * 2;
    if (node0 >= n) return;
    bool two = (node0 + 1 < n);
    const float4* r0 = (const float4*)(in + (size_t)node0 * KSTR);
    const float4* r1 = two ? (const float4*)(in + (size_t)(node0 + 1) * KSTR) : r0;
    const float4* Wf4 = (const float4*)Ws;
    float4 acc0 = {0.f, 0.f, 0.f, 0.f}, acc1 = {0.f, 0.f, 0.f, 0.f};
#pragma unroll
    for (int k0 = 0; k0 < K / 4; ++k0) {
        float4 x0 = r0[k0];
        float4 x1 = r1[k0];
#pragma unroll
        for (int kk = 0; kk < 4; ++kk) {
            float4 wv = Wf4[(k0 * 4 + kk) * CG + cg];
            float a = (&x0.x)[kk], b = (&x1.x)[kk];
            acc0.x += a * wv.x; acc0.y += a * wv.y; acc0.z += a * wv.z; acc0.w += a * wv.w;
            acc1.x += b * wv.x; acc1.y += b * wv.y; acc1.z += b * wv.z; acc1.w += b * wv.w;
        }
    }
    float dn0 = dis[node0];
    float dn1 = two ? dis[node0 + 1] : 0.f;
    acc0.x *= dn0; acc0.y *= dn0; acc0.z *= dn0; acc0.w *= dn0;
    acc1.x *= dn1; acc1.y *= dn1; acc1.z *= dn1; acc1.w *= dn1;
    if (EPI_BIAS_RELU) {
        float4 bv = ((const float4*)bias)[cg];
        acc0.x = fmaxf(acc0.x + bv.x, 0.f); acc0.y = fmaxf(acc0.y + bv.y, 0.f);
        acc0.z = fmaxf(acc0.z + bv.z, 0.f); acc0.w = fmaxf(acc0.w + bv.w, 0.f);
        acc1.x = fmaxf(acc1.x + bv.x, 0.f); acc1.y = fmaxf(acc1.y + bv.y, 0.f);
        acc1.z = fmaxf(acc1.z + bv.z, 0.f); acc1.w = fmaxf(acc1.w + bv.w, 0.f);
    }
    if constexpr (std::is_same<OUT_T, __half>::value) {
        union { __half2 h[2]; uint2 u; } p0, p1;
        p0.h[0] = __floats2half2_rn(acc0.x, acc0.y);
        p0.h[1] = __floats2half2_rn(acc0.z, acc0.w);
        *(uint2*)(out + (size_t)node0 * FOUT + cg * 4) = p0.u;
        if (two) {
            p1.h[0] = __floats2half2_rn(acc1.x, acc1.y);
            p1.h[1] = __floats2half2_rn(acc1.z, acc1.w);
            *(uint2*)(out + (size_t)(node0 + 1) * FOUT + cg * 4) = p1.u;
        }
    } else {
        ((float4*)(out + (size_t)node0 * FOUT))[cg] = acc0;
        if (two) ((float4*)(out + (size_t)(node0 + 1) * FOUT))[cg] = acc1;
    }
}

// scalar GEMM for FOUT=2 (tiny)
template<int KSTR, int K, int FOUT>
__global__ __launch_bounds__(THREADS)
void k_gemm_sm(const float* __restrict__ in, const float* __restrict__ W,
               const float* __restrict__ dis, float* __restrict__ out, int n) {
    __shared__ float Ws[K * FOUT];
    for (int i = threadIdx.x; i < K * FOUT; i += THREADS) Ws[i] = W[i];
    __syncthreads();
    int gid = blockIdx.x * THREADS + threadIdx.x;
    int node = gid / FOUT, col = gid % FOUT;
    if (node >= n) return;
    const float* xr = in + (size_t)node * KSTR;
    float acc = 0.0f;
#pragma unroll
    for (int k = 0; k < K; ++k) acc += xr[k] * Ws[k * FOUT + col];
    out[(size_t)node * FOUT + col] = acc * dis[node];
}

// ---------------- pooling + log_softmax ----------------

__global__ void k_zero2(float* __restrict__ sums, float* __restrict__ cnts, int ng) {
    int i = blockIdx.x * blockDim.x + threadIdx.x;
    if (i < ng) {
        sums[i * 2 + 0] = 0.0f;
        sums[i * 2 + 1] = 0.0f;
        cnts[i] = 0.0f;
    }
}

__global__ __launch_bounds__(THREADS)
void k_pool(const float* __restrict__ h4, const int* __restrict__ batch,
            float* __restrict__ sums, float* __restrict__ cnts, int n) {
    int i0 = (blockIdx.x * blockDim.x + threadIdx.x) * 8;
    if (i0 >= n) return;
    int end = min(i0 + 8, n);
    int g = batch[i0];
    float v0 = 0.f, v1 = 0.f, c = 0.f;
    for (int i = i0; i < end; ++i) {
        int gi = batch[i];
        if (gi != g) {
            atomicAdd(&sums[g * 2 + 0], v0);
            atomicAdd(&sums[g * 2 + 1], v1);
            atomicAdd(&cnts[g], c);
            g = gi; v0 = 0.f; v1 = 0.f; c = 0.f;
        }
        v0 += h4[(size_t)i * 2 + 0];
        v1 += h4[(size_t)i * 2 + 1];
        c += 1.0f;
    }
    atomicAdd(&sums[g * 2 + 0], v0);
    atomicAdd(&sums[g * 2 + 1], v1);
    atomicAdd(&cnts[g], c);
}

__global__ void k_logsoftmax(const float* __restrict__ sums, const float* __restrict__ cnts,
                             float* __restrict__ out, int ng) {
    int g = blockIdx.x * blockDim.x + threadIdx.x;
    if (g >= ng) return;
    float c = fmaxf(cnts[g], 1.0f);
    float p0 = sums[g * 2 + 0] / c;
    float p1 = sums[g * 2 + 1] / c;
    float m = fmaxf(p0, p1);
    float l = m + logf(expf(p0 - m) + expf(p1 - m));
    out[g * 2 + 0] = p0 - l;
    out[g * 2 + 1] = p1 - l;
}

// ---------------- launch ----------------

static inline int nblk(long long t) { return (int)((t + THREADS - 1) / THREADS); }

extern "C" void kernel_launch(void* const* d_in, const int* in_sizes, int n_in,
                              void* d_out, int out_size, void* d_ws, size_t ws_size,
                              hipStream_t stream) {
    const float* x     = (const float*)d_in[0];
    const int*   ei    = (const int*)d_in[1];
    const int*   batch = (const int*)d_in[2];
    const float* W1 = (const float*)d_in[4];
    const float* b1 = (const float*)d_in[5];
    const float* W2 = (const float*)d_in[6];
    const float* b2 = (const float*)d_in[7];
    const float* W3 = (const float*)d_in[8];
    const float* b3 = (const float*)d_in[9];
    const float* W4 = (const float*)d_in[10];
    const float* b4 = (const float*)d_in[11];

    const int n  = in_sizes[0] / 14;
    const int e  = in_sizes[1] / 2;
    const int ng = out_size / 2;
    const int* src = ei;
    const int* dst = ei + e;
    const int nb = nblk(n);
    const int nbuck = (n + (1 << BSH) - 1) >> BSH;   // 25 for n=100000

    char* ws = (char*)d_ws;
    size_t off_b = 0;
    auto alloc = [&](size_t bytes) -> char* {
        char* p = ws + off_b;
        off_b = (off_b + bytes + 255) & ~(size_t)255;
        return p;
    };
    int*     cnt  = (int*)alloc((size_t)(n + MAXB) * 4);        // in-degree + bucket counts
    int*     bcnt = cnt + n;
    float*   dis  = (float*)alloc((size_t)n * 4);
    int*     csr  = (int*)alloc((size_t)n * CAP * 4);           // 32 MB buckets
    __half2* xs16 = (__half2*)alloc((size_t)n * 8 * 4);         // n x 16 f16
    float*   agg1 = (float*)alloc((size_t)n * 16 * 4);          // n x 16 f32
    float*   hbuf = (float*)alloc((size_t)n * 64 * 4);          // h1/h2/h3 (reused); aliases pairbuf
    __half2* hw16 = (__half2*)alloc((size_t)n * 32 * 4);        // n x 64 f16 (reused n x 32)
    float*   hw4  = (float*)alloc((size_t)n * 2 * 4);
    float*   h4   = (float*)alloc((size_t)n * 2 * 4);
    float*   sums = (float*)alloc((size_t)ng * 2 * 4);
    float*   cnts = (float*)alloc((size_t)ng * 4);
    int*     pairs = (int*)hbuf;   // 25*137216*4 = 13.7 MB < 25.6 MB; dead once hbuf first written
    (void)ws_size; (void)n_in;

    // --- CSR build: zero, partition (read edges once), windowed scatter ---
    k_zero_i<<<nblk(n + MAXB), THREADS, 0, stream>>>(cnt, n + MAXB);
    k_part<<<nblk(((long long)e + 7) / 8), THREADS, 0, stream>>>(src, dst, bcnt, pairs, e, nbuck);
    k_scat<<<nbuck, 1024, 0, stream>>>(pairs, bcnt, cnt, csr);
    k_dis_xs<<<nb, THREADS, 0, stream>>>(cnt, x, dis, xs16, n);

    // --- Layer 1 (pre-aggregate at F=16 f16): SG=4, 8B lanes ---
    k_gather_pk<4, 2, true, false, false, false><<<nblk((long long)n * 4), THREADS, 0, stream>>>(
        xs16, cnt, csr, dis, nullptr, agg1, n);
    k_gemm_rb<14, 16, 16, 64, true, float><<<nblk((long long)(n / 2 + 1) * 16), THREADS, 0, stream>>>(
        agg1, W1, dis, b1, hbuf, n);                                  // h1 (pairs now dead)

    // --- Layer 2: SG=8, 16B lanes ---
    k_gemm_rb<64, 64, 64, 64, false, __half><<<nblk((long long)(n / 2 + 1) * 16), THREADS, 0, stream>>>(
        hbuf, W2, dis, nullptr, (__half*)hw16, n);                    // hw2' f16
    k_gather_pk<8, 4, false, true, true, true><<<nblk((long long)n * 8), THREADS, 0, stream>>>(
        hw16, cnt, csr, dis, b2, hbuf, n);                            // h2 (reuse)

    // --- Layer 3: SG=4, 16B lanes ---
    k_gemm_rb<64, 64, 64, 32, false, __half><<<nblk((long long)(n / 2 + 1) * 8), THREADS, 0, stream>>>(
        hbuf, W3, dis, nullptr, (__half*)hw16, n);                    // hw3' f16
    k_gather_pk<4, 4, false, true, true, true><<<nblk((long long)n * 4), THREADS, 0, stream>>>(
        hw16, cnt, csr, dis, b3, hbuf, n);                            // h3 (stride 32, reuse)

    // --- Layer 4 ---
    k_gemm_sm<32, 32, 2><<<nblk((long long)n * 2), THREADS, 0, stream>>>(
        hbuf, W4, dis, hw4, n);
    k_gather2<<<nb, THREADS, 0, stream>>>(hw4, cnt, csr, dis, b4, h4, n);

    // --- Pool + log_softmax ---
    k_zero2<<<nblk(ng), THREADS, 0, stream>>>(sums, cnts, ng);
    k_pool<<<nblk((n + 7) / 8), THREADS, 0, stream>>>(h4, batch, sums, cnts, n);
    k_logsoftmax<<<nblk(ng), THREADS, 0, stream>>>(sums, cnts, (float*)d_out, ng);
}

// Round 8
// 351.758 us; speedup vs baseline: 1.8379x; 1.8379x over previous
//
#include <hip/hip_runtime.h>
#include <hip/hip_fp16.h>
#include <math.h>
#include <type_traits>

static constexpr int THREADS = 256;
static constexpr int CAP   = 80;      // per-node neighbor capacity; in-deg ~Poisson(32), P(>=80) ~ 1e-12
static constexpr int BSH   = 10;      // dst-bucket shift: 1024 nodes/bucket
static constexpr int SUBS  = 8;       // sub-windows per bucket (128 nodes each)
static constexpr int SUBN  = 128;     // nodes per sub-window
static constexpr int CAPB  = 34816;   // per-bucket pair capacity (mean 32653 + 12 sigma, mult of 4)
static constexpr int MAXB  = 128;     // max buckets supported (98 used)

// ---------------- zero bucket counters ----------------

__global__ void k_zero_i(int* __restrict__ p, int n) {
    int i = blockIdx.x * blockDim.x + threadIdx.x;
    if (i < n) p[i] = 0;
}

// ---------------- phase 1: partition edges into dst-range bucket streams ----------------
// Read edges ONCE; LDS histogram -> one global atomicAdd per (bucket, block);
// pairs packed as ((d & 1023) << 17) | s   (requires n <= 131072).

__global__ __launch_bounds__(THREADS)
void k_part(const int* __restrict__ src, const int* __restrict__ dst,
            int* __restrict__ bcnt, int* __restrict__ pairs, int e, int nbuck) {
    __shared__ int hist[MAXB];
    __shared__ int base_s[MAXB];
    for (int i = threadIdx.x; i < nbuck; i += THREADS) hist[i] = 0;
    __syncthreads();

    int i0 = (blockIdx.x * THREADS + (int)threadIdx.x) * 8;
    int ss[8], dd[8], bb[8], rk[8];
    int c8 = 0;
    if (i0 < e) {
        c8 = min(8, e - i0);
        if (c8 == 8) {
            int4 d0 = ((const int4*)(dst + i0))[0];
            int4 d1 = ((const int4*)(dst + i0))[1];
            int4 s0 = ((const int4*)(src + i0))[0];
            int4 s1 = ((const int4*)(src + i0))[1];
            dd[0]=d0.x; dd[1]=d0.y; dd[2]=d0.z; dd[3]=d0.w;
            dd[4]=d1.x; dd[5]=d1.y; dd[6]=d1.z; dd[7]=d1.w;
            ss[0]=s0.x; ss[1]=s0.y; ss[2]=s0.z; ss[3]=s0.w;
            ss[4]=s1.x; ss[5]=s1.y; ss[6]=s1.z; ss[7]=s1.w;
        } else {
            for (int j = 0; j < c8; ++j) { dd[j] = dst[i0 + j]; ss[j] = src[i0 + j]; }
        }
        for (int j = 0; j < c8; ++j) {
            bb[j] = dd[j] >> BSH;
            rk[j] = atomicAdd(&hist[bb[j]], 1);
        }
    }
    __syncthreads();
    for (int i = threadIdx.x; i < nbuck; i += THREADS)
        base_s[i] = hist[i] ? atomicAdd(&bcnt[i], hist[i]) : 0;
    __syncthreads();
    for (int j = 0; j < c8; ++j) {
        int idx = base_s[bb[j]] + rk[j];
        if (idx < CAPB)
            pairs[(size_t)bb[j] * CAPB + idx] = ((dd[j] & ((1 << BSH) - 1)) << 17) | ss[j];
    }
}

// ---------------- phase 2: LDS-staged scatter; block = (bucket, sub-window of 128 nodes) ----------
// Filter bucket stream for my 128 nodes -> LDS atomics into 40 KB slab -> coalesced dump.
// Also emits cnt[] (degree) directly, so no global cnt zeroing pass.

__global__ __launch_bounds__(THREADS)
void k_scat2(const int* __restrict__ pairs, const int* __restrict__ bcnt,
             int* __restrict__ cnt, int* __restrict__ csr, int n) {
    __shared__ int slab[SUBN * CAP];   // 40 KB
    __shared__ int lcnt[SUBN];
    int bucket = blockIdx.x / SUBS;
    int sub    = blockIdx.x % SUBS;
    int gnode0 = (bucket << BSH) + sub * SUBN;
    if (gnode0 >= n) return;
    for (int i = threadIdx.x; i < SUBN; i += THREADS) lcnt[i] = 0;
    __syncthreads();

    int m = min(bcnt[bucket], CAPB);
    const int* pp = pairs + (size_t)bucket * CAPB;
    for (int i0 = (int)threadIdx.x * 4; i0 < m; i0 += THREADS * 4) {
        int k = min(4, m - i0);
        int v[4];
        if (k == 4) {
            int4 a = *(const int4*)(pp + i0);
            v[0] = a.x; v[1] = a.y; v[2] = a.z; v[3] = a.w;
        } else {
            for (int j = 0; j < k; ++j) v[j] = pp[i0 + j];
        }
#pragma unroll
        for (int j = 0; j < 4; ++j) {
            if (j < k) {
                int dl = v[j] >> 17;               // 10-bit local node
                if ((dl >> 7) == sub) {
                    int ln = dl & (SUBN - 1);
                    int p = atomicAdd(&lcnt[ln], 1);
                    if (p < CAP) slab[ln * CAP + p] = v[j] & 0x1FFFF;
                }
            }
        }
    }
    __syncthreads();

    // coalesced dump of slab -> csr rows [gnode0, gnode0+128)
    size_t gbase = (size_t)gnode0 * CAP;
    for (int idx = threadIdx.x; idx < SUBN * CAP; idx += THREADS) {
        int node = gnode0 + idx / CAP;
        if (node < n) csr[gbase + idx] = slab[idx];
    }
    for (int i = threadIdx.x; i < SUBN; i += THREADS) {
        int node = gnode0 + i;
        if (node < n) cnt[node] = min(lcnt[i], CAP);
    }
}

// ---------------- dis = rsqrt(deg+1); xs[n][16] = f16(dis*x) (fused) ----------------

__global__ __launch_bounds__(THREADS)
void k_dis_xs(const int* __restrict__ deg, const float* __restrict__ x,
              float* __restrict__ dis, __half2* __restrict__ xs, int n) {
    int i = blockIdx.x * blockDim.x + threadIdx.x;
    if (i >= n) return;
    float dn = rsqrtf((float)(deg[i] + 1));
    dis[i] = dn;
    const float* xr = x + (size_t)i * 14;
    __half2* o = xs + (size_t)i * 8;
#pragma unroll
    for (int fl = 0; fl < 7; ++fl) {
        float2 v;
        v.x = dn * xr[fl * 2];
        v.y = dn * xr[fl * 2 + 1];
        o[fl] = __float22half2_rn(v);
    }
    o[7] = __float22half2_rn(make_float2(0.f, 0.f));
}

// ---------------- CSR gather, packed-f16 accumulate ----------------

template<int SG, int HPL, bool SELF_SCALE, bool EPI_SCALE, bool BIAS, bool RELU>
__global__ __launch_bounds__(THREADS)
void k_gather_pk(const __half2* __restrict__ hw, const int* __restrict__ deg,
                 const int* __restrict__ csr, const float* __restrict__ dis,
                 const float* __restrict__ bias, float* __restrict__ out, int n) {
    constexpr int RS = SG * HPL;   // row stride in half2 units
    int tid = blockIdx.x * THREADS + threadIdx.x;
    int node = tid / SG;
    int fl = tid % SG;
    if (node >= n) return;
    size_t o = (size_t)node * CAP;
    int dg = deg[node];
    float dn = dis[node];

    auto loadrow = [&](int s, __half2* r) {
        const __half2* p = hw + (size_t)s * RS + fl * HPL;
        if constexpr (HPL == 4) {
            union { uint4 u; __half2 h[4]; } t;
            t.u = *(const uint4*)p;
            r[0] = t.h[0]; r[1] = t.h[1]; r[2] = t.h[2]; r[3] = t.h[3];
        } else if constexpr (HPL == 2) {
            union { uint2 u; __half2 h[2]; } t;
            t.u = *(const uint2*)p;
            r[0] = t.h[0]; r[1] = t.h[1];
        } else {
            r[0] = *p;
        }
    };

    // self in f32
    float2 self[HPL];
    {
        __half2 r[HPL];
        loadrow(node, r);
#pragma unroll
        for (int q = 0; q < HPL; ++q) {
            self[q] = __half22float2(r[q]);
            if (SELF_SCALE) { self[q].x *= dn; self[q].y *= dn; }
        }
    }

    __half2 z = __float2half2_rn(0.f);
    __half2 c0[HPL], c1[HPL], c2[HPL], c3[HPL];
#pragma unroll
    for (int q = 0; q < HPL; ++q) { c0[q] = z; c1[q] = z; c2[q] = z; c3[q] = z; }

    int base = 0;
    for (; base + SG <= dg; base += SG) {
        int cs = csr[o + base + fl];
#pragma unroll
        for (int t = 0; t < SG; t += 4) {
            int s0 = __shfl(cs, t, SG),     s1 = __shfl(cs, t + 1, SG);
            int s2 = __shfl(cs, t + 2, SG), s3 = __shfl(cs, t + 3, SG);
            __half2 r0[HPL], r1[HPL], r2[HPL], r3[HPL];
            loadrow(s0, r0); loadrow(s1, r1); loadrow(s2, r2); loadrow(s3, r3);
#pragma unroll
            for (int q = 0; q < HPL; ++q) {
                c0[q] = __hadd2(c0[q], r0[q]);
                c1[q] = __hadd2(c1[q], r1[q]);
                c2[q] = __hadd2(c2[q], r2[q]);
                c3[q] = __hadd2(c3[q], r3[q]);
            }
        }
    }
    int rem = dg - base;
    if (rem > 0) {
        int cs = (fl < rem) ? csr[o + base + fl] : 0;
        int t = 0;
        for (; t + 4 <= rem; t += 4) {
            int s0 = __shfl(cs, t, SG),     s1 = __shfl(cs, t + 1, SG);
            int s2 = __shfl(cs, t + 2, SG), s3 = __shfl(cs, t + 3, SG);
            __half2 r0[HPL], r1[HPL], r2[HPL], r3[HPL];
            loadrow(s0, r0); loadrow(s1, r1); loadrow(s2, r2); loadrow(s3, r3);
#pragma unroll
            for (int q = 0; q < HPL; ++q) {
                c0[q] = __hadd2(c0[q], r0[q]);
                c1[q] = __hadd2(c1[q], r1[q]);
                c2[q] = __hadd2(c2[q], r2[q]);
                c3[q] = __hadd2(c3[q], r3[q]);
            }
        }
        for (; t < rem; ++t) {
            int s = __shfl(cs, t, SG);
            __half2 r[HPL];
            loadrow(s, r);
#pragma unroll
            for (int q = 0; q < HPL; ++q) c0[q] = __hadd2(c0[q], r[q]);
        }
    }

    float* op = out + (size_t)node * 2 * RS + fl * 2 * HPL;
#pragma unroll
    for (int q = 0; q < HPL; ++q) {
        float2 v0 = __half22float2(c0[q]), v1 = __half22float2(c1[q]);
        float2 v2 = __half22float2(c2[q]), v3 = __half22float2(c3[q]);
        float2 v;
        v.x = self[q].x + (v0.x + v1.x) + (v2.x + v3.x);
        v.y = self[q].y + (v0.y + v1.y) + (v2.y + v3.y);
        if (EPI_SCALE) { v.x *= dn; v.y *= dn; }
        if (BIAS) {
            float2 b = ((const float2*)bias)[fl * HPL + q];
            v.x += b.x; v.y += b.y;
        }
        if (RELU) { v.x = fmaxf(v.x, 0.f); v.y = fmaxf(v.y, 0.f); }
        op[q * 2 + 0] = v.x;
        op[q * 2 + 1] = v.y;
    }
}

// F=2 gather: one thread per node, f32 float2 rows (800 KB buffer, L2-resident)
__global__ __launch_bounds__(THREADS)
void k_gather2(const float* __restrict__ hw, const int* __restrict__ deg,
               const int* __restrict__ csr, const float* __restrict__ dis,
               const float* __restrict__ b, float* __restrict__ out, int n) {
    int i = blockIdx.x * blockDim.x + threadIdx.x;
    if (i >= n) return;
    const float2* h2 = (const float2*)hw;
    size_t o = (size_t)i * CAP;
    int dg = deg[i];
    float2 a = h2[i];
    float x0 = a.x, y0 = a.y, x1 = 0.f, y1 = 0.f, x2 = 0.f, y2 = 0.f, x3 = 0.f, y3 = 0.f;
    int j = 0;
    for (; j + 4 <= dg; j += 4) {
        int s0 = csr[o + j], s1 = csr[o + j + 1], s2 = csr[o + j + 2], s3 = csr[o + j + 3];
        float2 v0 = h2[s0], v1 = h2[s1], v2 = h2[s2], v3 = h2[s3];
        x0 += v0.x; y0 += v0.y;
        x1 += v1.x; y1 += v1.y;
        x2 += v2.x; y2 += v2.y;
        x3 += v3.x; y3 += v3.y;
    }
    for (; j < dg; ++j) {
        int s = csr[o + j];
        float2 v = h2[s];
        x0 += v.x; y0 += v.y;
    }
    float dn = dis[i];
    out[(size_t)i * 2 + 0] = ((x0 + x1) + (x2 + x3)) * dn + b[0];
    out[(size_t)i * 2 + 1] = ((y0 + y1) + (y2 + y3)) * dn + b[1];
}

// ---------------- register-blocked GEMM: 2 nodes x 4 cols per thread ----------------

template<int KW, int K, int KSTR, int FOUT, bool EPI_BIAS_RELU, typename OUT_T>
__global__ __launch_bounds__(THREADS)
void k_gemm_rb(const float* __restrict__ in, const float* __restrict__ W,
               const float* __restrict__ dis, const float* __restrict__ bias,
               OUT_T* __restrict__ out, int n) {
    constexpr int CG = FOUT / 4;
    __shared__ float Ws[K * FOUT];
    for (int i = threadIdx.x; i < K * FOUT; i += THREADS) {
        int r = i / FOUT;
        Ws[i] = (r < KW) ? W[i] : 0.0f;
    }
    __syncthreads();
    int gid = blockIdx.x * THREADS + threadIdx.x;
    int pair = gid / CG, cg = gid % CG;
    int node0 = pair * 2;
    if (node0 >= n) return;
    bool two = (node0 + 1 < n);
    const float4* r0 = (const float4*)(in + (size_t)node0 * KSTR);
    const float4* r1 = two ? (const float4*)(in + (size_t)(node0 + 1) * KSTR) : r0;
    const float4* Wf4 = (const float4*)Ws;
    float4 acc0 = {0.f, 0.f, 0.f, 0.f}, acc1 = {0.f, 0.f, 0.f, 0.f};
#pragma unroll
    for (int k0 = 0; k0 < K / 4; ++k0) {
        float4 x0 = r0[k0];
        float4 x1 = r1[k0];
#pragma unroll
        for (int kk = 0; kk < 4; ++kk) {
            float4 wv = Wf4[(k0 * 4 + kk) * CG + cg];
            float a = (&x0.x)[kk], b = (&x1.x)[kk];
            acc0.x += a * wv.x; acc0.y += a * wv.y; acc0.z += a * wv.z; acc0.w += a * wv.w;
            acc1.x += b * wv.x; acc1.y += b * wv.y; acc1.z += b * wv.z; acc1.w += b * wv.w;
        }
    }
    float dn0 = dis[node0];
    float dn1 = two ? dis[node0 + 1] : 0.f;
    acc0.x *= dn0; acc0.y *= dn0; acc0.z *= dn0; acc0.w *= dn0;
    acc1.x *= dn1; acc1.y *= dn1; acc1.z *= dn1; acc1.w *= dn1;
    if (EPI_BIAS_RELU) {
        float4 bv = ((const float4*)bias)[cg];
        acc0.x = fmaxf(acc0.x + bv.x, 0.f); acc0.y = fmaxf(acc0.y + bv.y, 0.f);
        acc0.z = fmaxf(acc0.z + bv.z, 0.f); acc0.w = fmaxf(acc0.w + bv.w, 0.f);
        acc1.x = fmaxf(acc1.x + bv.x, 0.f); acc1.y = fmaxf(acc1.y + bv.y, 0.f);
        acc1.z = fmaxf(acc1.z + bv.z, 0.f); acc1.w = fmaxf(acc1.w + bv.w, 0.f);
    }
    if constexpr (std::is_same<OUT_T, __half>::value) {
        union { __half2 h[2]; uint2 u; } p0, p1;
        p0.h[0] = __floats2half2_rn(acc0.x, acc0.y);
        p0.h[1] = __floats2half2_rn(acc0.z, acc0.w);
        *(uint2*)(out + (size_t)node0 * FOUT + cg * 4) = p0.u;
        if (two) {
            p1.h[0] = __floats2half2_rn(acc1.x, acc1.y);
            p1.h[1] = __floats2half2_rn(acc1.z, acc1.w);
            *(uint2*)(out + (size_t)(node0 + 1) * FOUT + cg * 4) = p1.u;
        }
    } else {
        ((float4*)(out + (size_t)node0 * FOUT))[cg] = acc0;
        if (two) ((float4*)(out + (size_t)(node0 + 1) * FOUT))[cg] = acc1;
    }
}

// scalar GEMM for FOUT=2 (tiny)
template<int KSTR, int K, int FOUT>
__global__ __launch_bounds__(THREADS)
void k_gemm_sm(const float* __restrict__ in, const float* __restrict__ W,
               const float* __restrict__ dis, float* __restrict__ out, int n) {
    __shared__ float Ws[K * FOUT];
    for (int i = threadIdx.x; i < K * FOUT; i += THREADS) Ws[i] = W[i];
    __syncthreads();
    int gid = blockIdx.x * THREADS + threadIdx.x;
    int node = gid / FOUT, col = gid % FOUT;
    if (node >= n) return;
    const float* xr = in + (size_t)node * KSTR;
    float acc = 0.0f;
#pragma unroll
    for (int k = 0; k < K; ++k) acc += xr[k] * Ws[k * FOUT + col];
    out[(size_t)node * FOUT + col] = acc * dis[node];
}

// ---------------- pooling + log_softmax ----------------

__global__ void k_zero2(float* __restrict__ sums, float* __restrict__ cnts, int ng) {
    int i = blockIdx.x * blockDim.x + threadIdx.x;
    if (i < ng) {
        sums[i * 2 + 0] = 0.0f;
        sums[i * 2 + 1] = 0.0f;
        cnts[i] = 0.0f;
    }
}

__global__ __launch_bounds__(THREADS)
void k_pool(const float* __restrict__ h4, const int* __restrict__ batch,
            float* __restrict__ sums, float* __restrict__ cnts, int n) {
    int i0 = (blockIdx.x * blockDim.x + threadIdx.x) * 8;
    if (i0 >= n) return;
    int end = min(i0 + 8, n);
    int g = batch[i0];
    float v0 = 0.f, v1 = 0.f, c = 0.f;
    for (int i = i0; i < end; ++i) {
        int gi = batch[i];
        if (gi != g) {
            atomicAdd(&sums[g * 2 + 0], v0);
            atomicAdd(&sums[g * 2 + 1], v1);
            atomicAdd(&cnts[g], c);
            g = gi; v0 = 0.f; v1 = 0.f; c = 0.f;
        }
        v0 += h4[(size_t)i * 2 + 0];
        v1 += h4[(size_t)i * 2 + 1];
        c += 1.0f;
    }
    atomicAdd(&sums[g * 2 + 0], v0);
    atomicAdd(&sums[g * 2 + 1], v1);
    atomicAdd(&cnts[g], c);
}

__global__ void k_logsoftmax(const float* __restrict__ sums, const float* __restrict__ cnts,
                             float* __restrict__ out, int ng) {
    int g = blockIdx.x * blockDim.x + threadIdx.x;
    if (g >= ng) return;
    float c = fmaxf(cnts[g], 1.0f);
    float p0 = sums[g * 2 + 0] / c;
    float p1 = sums[g * 2 + 1] / c;
    float m = fmaxf(p0, p1);
    float l = m + logf(expf(p0 - m) + expf(p1 - m));
    out[g * 2 + 0] = p0 - l;
    out[g * 2 + 1] = p1 - l;
}

// ---------------- launch ----------------

static inline int nblk(long long t) { return (int)((t + THREADS - 1) / THREADS); }

extern "C" void kernel_launch(void* const* d_in, const int* in_sizes, int n_in,
                              void* d_out, int out_size, void* d_ws, size_t ws_size,
                              hipStream_t stream) {
    const float* x     = (const float*)d_in[0];
    const int*   ei    = (const int*)d_in[1];
    const int*   batch = (const int*)d_in[2];
    const float* W1 = (const float*)d_in[4];
    const float* b1 = (const float*)d_in[5];
    const float* W2 = (const float*)d_in[6];
    const float* b2 = (const float*)d_in[7];
    const float* W3 = (const float*)d_in[8];
    const float* b3 = (const float*)d_in[9];
    const float* W4 = (const float*)d_in[10];
    const float* b4 = (const float*)d_in[11];

    const int n  = in_sizes[0] / 14;
    const int e  = in_sizes[1] / 2;
    const int ng = out_size / 2;
    const int* src = ei;
    const int* dst = ei + e;
    const int nb = nblk(n);
    const int nbuck = (n + (1 << BSH) - 1) >> BSH;   // 98 for n=100000

    char* ws = (char*)d_ws;
    size_t off_b = 0;
    auto alloc = [&](size_t bytes) -> char* {
        char* p = ws + off_b;
        off_b = (off_b + bytes + 255) & ~(size_t)255;
        return p;
    };
    int*     cnt  = (int*)alloc((size_t)n * 4);                 // in-degree (written by k_scat2)
    int*     bcnt = (int*)alloc((size_t)MAXB * 4);
    float*   dis  = (float*)alloc((size_t)n * 4);
    int*     csr  = (int*)alloc((size_t)n * CAP * 4);           // 32 MB CAP-strided rows
    __half2* xs16 = (__half2*)alloc((size_t)n * 8 * 4);         // n x 16 f16
    float*   agg1 = (float*)alloc((size_t)n * 16 * 4);          // n x 16 f32
    float*   hbuf = (float*)alloc((size_t)n * 64 * 4);          // h1/h2/h3 (reused); aliases pairbuf
    __half2* hw16 = (__half2*)alloc((size_t)n * 32 * 4);        // n x 64 f16 (reused n x 32)
    float*   hw4  = (float*)alloc((size_t)n * 2 * 4);
    float*   h4   = (float*)alloc((size_t)n * 2 * 4);
    float*   sums = (float*)alloc((size_t)ng * 2 * 4);
    float*   cnts = (float*)alloc((size_t)ng * 4);
    int*     pairs = (int*)hbuf;   // 98*34816*4 = 13.65 MB < 25.6 MB; dead before hbuf first written
    (void)ws_size; (void)n_in;

    // --- CSR build: zero bcnt, partition (read edges once), LDS-staged windowed scatter ---
    k_zero_i<<<1, THREADS, 0, stream>>>(bcnt, MAXB);
    k_part<<<nblk(((long long)e + 7) / 8), THREADS, 0, stream>>>(src, dst, bcnt, pairs, e, nbuck);
    k_scat2<<<nbuck * SUBS, THREADS, 0, stream>>>(pairs, bcnt, cnt, csr, n);
    k_dis_xs<<<nb, THREADS, 0, stream>>>(cnt, x, dis, xs16, n);

    // --- Layer 1 (pre-aggregate at F=16 f16): SG=4, 8B lanes ---
    k_gather_pk<4, 2, true, false, false, false><<<nblk((long long)n * 4), THREADS, 0, stream>>>(
        xs16, cnt, csr, dis, nullptr, agg1, n);
    k_gemm_rb<14, 16, 16, 64, true, float><<<nblk((long long)(n / 2 + 1) * 16), THREADS, 0, stream>>>(
        agg1, W1, dis, b1, hbuf, n);                                  // h1 (pairs now dead)

    // --- Layer 2: SG=8, 16B lanes ---
    k_gemm_rb<64, 64, 64, 64, false, __half><<<nblk((long long)(n / 2 + 1) * 16), THREADS, 0, stream>>>(
        hbuf, W2, dis, nullptr, (__half*)hw16, n);                    // hw2' f16
    k_gather_pk<8, 4, false, true, true, true><<<nblk((long long)n * 8), THREADS, 0, stream>>>(
        hw16, cnt, csr, dis, b2, hbuf, n);                            // h2 (reuse)

    // --- Layer 3: SG=4, 16B lanes ---
    k_gemm_rb<64, 64, 64, 32, false, __half><<<nblk((long long)(n / 2 + 1) * 8), THREADS, 0, stream>>>(
        hbuf, W3, dis, nullptr, (__half*)hw16, n);                    // hw3' f16
    k_gather_pk<4, 4, false, true, true, true><<<nblk((long long)n * 4), THREADS, 0, stream>>>(
        hw16, cnt, csr, dis, b3, hbuf, n);                            // h3 (stride 32, reuse)

    // --- Layer 4 ---
    k_gemm_sm<32, 32, 2><<<nblk((long long)n * 2), THREADS, 0, stream>>>(
        hbuf, W4, dis, hw4, n);
    k_gather2<<<nb, THREADS, 0, stream>>>(hw4, cnt, csr, dis, b4, h4, n);

    // --- Pool + log_softmax ---
    k_zero2<<<nblk(ng), THREADS, 0, stream>>>(sums, cnts, ng);
    k_pool<<<nblk((n + 7) / 8), THREADS, 0, stream>>>(h4, batch, sums, cnts, n);
    k_logsoftmax<<<nblk(ng), THREADS, 0, stream>>>(sums, cnts, (float*)d_out, ng);
}